// Round 1
// 427.905 us; speedup vs baseline: 1.0294x; 1.0294x over previous
//
#include <hip/hip_runtime.h>
#include <hip/hip_bf16.h>

typedef short short8 __attribute__((ext_vector_type(8)));
typedef float floatx4 __attribute__((ext_vector_type(4)));

constexpr int Bn = 128, Tn = 2048, DPn = 256, DQn = 256, DOn = 256;
constexpr int NCH = Tn / 64;   // 32 t-chunks of 64 per batch row

__device__ inline unsigned pk2(float x, float y) {
    __hip_bfloat162 h = __float22bfloat162_rn(make_float2(x, y));  // v_cvt_pk_bf16_f32
    return *(unsigned*)&h;   // low 16 = x, high 16 = y
}
__device__ inline float fast_tanh(float x) {
    float e = __expf(2.0f * x);
    return 1.0f - 2.0f / (e + 1.0f);
}

// ---------------- Kernel 0 (merged): blocks [0,64): W_q f32->bf16 cvt
//                                     blocks [64,192): base[b][d] = W_p_r[d]·[p,h] + b_p_r[d] + b_q[d]
__global__ __launch_bounds__(256) void prep_kernel(const float* __restrict__ wq,
                                                   unsigned short* __restrict__ wqbf,
                                                   const float* __restrict__ input_p,
                                                   const float* __restrict__ h_tm1,
                                                   const float* __restrict__ Wpr,
                                                   const float* __restrict__ bpr,
                                                   const float* __restrict__ bq,
                                                   float* __restrict__ base) {
    __shared__ float v[512];
    int tid = threadIdx.x;
    if (blockIdx.x < 64) {
        int idx = blockIdx.x * 256 + tid;
        float4 x = ((const float4*)wq)[idx];
        ((uint2*)wqbf)[idx] = make_uint2(pk2(x.x, x.y), pk2(x.z, x.w));
        return;
    }
    int b = blockIdx.x - 64;
    v[tid]       = input_p[b * DPn + tid];
    v[256 + tid] = h_tm1[b * DOn + tid];
    __syncthreads();
    const float4* row = (const float4*)(Wpr + (size_t)tid * 512);
    const float4* vv  = (const float4*)v;
    float acc = 0.f;
#pragma unroll 8
    for (int i = 0; i < 128; i++) {
        float4 r = row[i], x = vv[i];
        acc = fmaf(r.x, x.x, acc);
        acc = fmaf(r.y, x.y, acc);
        acc = fmaf(r.z, x.z, acc);
        acc = fmaf(r.w, x.w, acc);
    }
    base[b * DOn + tid] = acc + bpr[tid] + bq[tid];
}

// ---------------- Kernel 1 (fused, single q read): stage f32 tile -> logits -> e' -> znum ----------------
// grid (32, 128): block = (b, t-chunk of 64). 256 threads = 4 waves.
// q is read from HBM exactly ONCE. Tile lives in LDS as f32, XOR-swizzled:
//   LDS[r*1024 + (cb ^ ((r&7)<<4))] holds q[t0+r][cb/4 .. cb/4+4)  (cb 16B-aligned)
// All accesses are 16B-granular so the XOR (bits 4..6) is consistent on write & read,
// and every wave-wide ds access lands at the uniform 8-dword/bank minimum (no conflicts).
__global__ __launch_bounds__(256, 2) void fused_kernel(const float* __restrict__ q,
                                                       const unsigned short* __restrict__ wqbf,
                                                       const float* __restrict__ base,
                                                       const float* __restrict__ wvec,
                                                       const float* __restrict__ matchb,
                                                       const int* __restrict__ maskq,
                                                       float* __restrict__ zpart,
                                                       float* __restrict__ spart,
                                                       float* __restrict__ mpart) {
    __shared__ __align__(16) float tile[64 * 256];   // 64 KiB swizzled f32 q-tile
    __shared__ __align__(16) float zp[4][256];       // 4 KiB znum partials
    __shared__ float partl[4][64];
    __shared__ float earr[64];

    int b = blockIdx.y, c = blockIdx.x;
    int t0 = c * 64;
    int tid = threadIdx.x;
    int w = tid >> 6, lane = tid & 63, l15 = lane & 15, quad = lane >> 4;
    char* tb = (char*)tile;

    // ---- stage: wave w copies rows [w*16, w*16+16) of the f32 tile; coalesced 1 KiB/row ----
    {
        const float* qsrc = q + ((size_t)b * Tn + t0) * DQn;
#pragma unroll
        for (int i = 0; i < 16; i++) {
            int r = w * 16 + i;
            float4 x = *(const float4*)(qsrc + (size_t)r * DQn + lane * 4);
            *(float4*)(tb + r * 1024 + ((lane * 16) ^ ((r & 7) << 4))) = x;
        }
    }

    // ---- B fragments (W_q bf16, L2-resident) + per-n scalars; overlaps stage latency ----
    short8 bfr[4][8];
    const unsigned short* bbase = wqbf + (size_t)(w * 64 + l15) * 256 + quad * 8;
#pragma unroll
    for (int nt = 0; nt < 4; nt++)
#pragma unroll
        for (int ks = 0; ks < 8; ks++)
            bfr[nt][ks] = *(const short8*)(bbase + nt * 16 * 256 + ks * 32);
    float bn[4], wn[4];
#pragma unroll
    for (int nt = 0; nt < 4; nt++) {
        int n = w * 64 + nt * 16 + l15;
        bn[nt] = base[b * DOn + n];
        wn[nt] = wvec[n];
    }
    __syncthreads();

    // ---- logits: A-frags read f32 from LDS, cvt to bf16 on the fly (bit-identical to staged cvt) ----
#pragma unroll
    for (int mt = 0; mt < 4; mt++) {
        int r = mt * 16 + l15;
        const char* ab = tb + r * 1024;
        int swz = (r & 7) << 4;
        short8 af[8];
#pragma unroll
        for (int ks = 0; ks < 8; ks++) {
            int cb = quad * 32 + ks * 128;
            float4 f0 = *(const float4*)(ab + (cb ^ swz));
            float4 f1 = *(const float4*)(ab + ((cb + 16) ^ swz));
            union { unsigned u[4]; short8 s; } cv;
            cv.u[0] = pk2(f0.x, f0.y);
            cv.u[1] = pk2(f0.z, f0.w);
            cv.u[2] = pk2(f1.x, f1.y);
            cv.u[3] = pk2(f1.z, f1.w);
            af[ks] = cv.s;
        }
        float prow[4] = {0.f, 0.f, 0.f, 0.f};
#pragma unroll
        for (int nt = 0; nt < 4; nt++) {
            floatx4 acc = {0.f, 0.f, 0.f, 0.f};
#pragma unroll
            for (int ks = 0; ks < 8; ks++)
                acc = __builtin_amdgcn_mfma_f32_16x16x32_bf16(af[ks], bfr[nt][ks], acc, 0, 0, 0);
#pragma unroll
            for (int rr = 0; rr < 4; rr++) {
                float g = fast_tanh(acc[rr] + bn[nt]);
                prow[rr] = fmaf(g, wn[nt], prow[rr]);
            }
        }
#pragma unroll
        for (int off = 1; off < 16; off <<= 1)
#pragma unroll
            for (int rr = 0; rr < 4; rr++) prow[rr] += __shfl_xor(prow[rr], off);
        if (l15 == 0) {
#pragma unroll
            for (int rr = 0; rr < 4; rr++) partl[w][mt * 16 + quad * 4 + rr] = prow[rr];
        }
    }
    __syncthreads();

    // ---- e' = exp(clip(lg)*m - 15)*m ; chunk max & sum ----
    if (tid < 64) {
        int t = tid;
        float lg = partl[0][t] + partl[1][t] + partl[2][t] + partl[3][t] + matchb[0];
        float m = (float)maskq[(size_t)b * Tn + t0 + t];
        float x = fminf(fmaxf(lg, -15.f), 15.f) * m;
        float e = __expf(x - 15.f) * m;
        earr[t] = e;
        float xm = x, es = e;
#pragma unroll
        for (int off = 1; off < 64; off <<= 1) {
            xm = fmaxf(xm, __shfl_xor(xm, off));
            es += __shfl_xor(es, off);
        }
        if (t == 0) {
            mpart[b * NCH + c] = xm;
            spart[b * NCH + c] = es;
        }
    }
    __syncthreads();

    // ---- znum from the LDS f32 tile (no global re-read): wave w sums rows [w*16, w*16+16),
    //      lane owns cols [lane*4, lane*4+4); conflict-free swizzled b128 reads ----
    {
        float a0 = 0.f, a1 = 0.f, a2 = 0.f, a3 = 0.f;
#pragma unroll
        for (int i = 0; i < 16; i++) {
            int r = w * 16 + i;
            float e = earr[r];  // broadcast read
            float4 x = *(const float4*)(tb + r * 1024 + ((lane * 16) ^ ((r & 7) << 4)));
            a0 = fmaf(e, x.x, a0);
            a1 = fmaf(e, x.y, a1);
            a2 = fmaf(e, x.z, a2);
            a3 = fmaf(e, x.w, a3);
        }
        *(float4*)&zp[w][lane * 4] = make_float4(a0, a1, a2, a3);
    }
    __syncthreads();
    {
        float zs = zp[0][tid] + zp[1][tid] + zp[2][tid] + zp[3][tid];
        zpart[((size_t)b * NCH + c) * DQn + tid] = zs;
    }
}

// ---------------- Kernel 2: exact denom + combine + concat ----------------
// z = (Σ_c znum_c) / (S' + 1e-6 * exp(mx - 15))   — identical to reference softmax math.
__global__ __launch_bounds__(256) void final_kernel(const float* __restrict__ input_p,
                                                    const float* __restrict__ zpart,
                                                    const float* __restrict__ spart,
                                                    const float* __restrict__ mpart,
                                                    float* __restrict__ out) {
    int b = blockIdx.x, tid = threadIdx.x;
    float S = 0.f, mx = -1e30f;
#pragma unroll 8
    for (int c = 0; c < NCH; c++) {
        S += spart[b * NCH + c];
        mx = fmaxf(mx, mpart[b * NCH + c]);
    }
    float denom = S + 1e-6f * __expf(mx - 15.f);
    float inv = 1.0f / denom;
    float zs = 0.f;
#pragma unroll 8
    for (int c = 0; c < NCH; c++) zs += zpart[((size_t)b * NCH + c) * DQn + tid];
    out[(size_t)b * 512 + tid] = input_p[(size_t)b * DPn + tid];
    out[(size_t)b * 512 + 256 + tid] = zs * inv;
}

extern "C" void kernel_launch(void* const* d_in, const int* in_sizes, int n_in,
                              void* d_out, int out_size, void* d_ws, size_t ws_size,
                              hipStream_t stream) {
    const float* input_p = (const float*)d_in[0];
    // d_in[1] = mask_p (unused by reference)
    const float* input_q = (const float*)d_in[2];
    const int*   mask_q  = (const int*)d_in[3];
    const float* h_tm1   = (const float*)d_in[4];
    const float* W_p_r   = (const float*)d_in[5];
    const float* b_p_r   = (const float*)d_in[6];
    const float* W_q     = (const float*)d_in[7];
    const float* b_q     = (const float*)d_in[8];
    const float* w       = (const float*)d_in[9];
    const float* match_b = (const float*)d_in[10];
    // d_in[11] = depth (unused, layer 0)
    float* out = (float*)d_out;

    char* ws = (char*)d_ws;
    unsigned short* wqbf = (unsigned short*)ws;                   // 128 KiB
    float* base  = (float*)(ws + 131072);                         // 128 KiB
    float* zpart = (float*)(ws + 262144);                         // 128*32*256*4 = 4 MiB
    float* spart = (float*)(ws + 262144 + 4194304);               // 16 KiB
    float* mpart = (float*)(ws + 262144 + 4194304 + 16384);       // 16 KiB

    prep_kernel<<<192, 256, 0, stream>>>(W_q, wqbf, input_p, h_tm1, W_p_r, b_p_r, b_q, base);
    fused_kernel<<<dim3(NCH, Bn), 256, 0, stream>>>(input_q, wqbf, base, w, match_b,
                                                    mask_q, zpart, spart, mpart);
    final_kernel<<<Bn, 256, 0, stream>>>(input_p, zpart, spart, mpart, out);
}